// Round 13
// baseline (314.100 us; speedup 1.0000x reference)
//
#include <hip/hip_runtime.h>
#include <math.h>

// ---------------- register-tiled GEMM: C[M,N] = A[M,K] @ B[K,N] ----------------
// BM=64 rows/block, CPB cols/block (gridDim.y = N/CPB). Per-thread MR rows x 8 cols.
// Threads NT = (64/MR) * (CPB/8). Single LDS buffer + register prefetch of the
// next chunk (issued right after barrier, lands under the math).
// iva != nullptr (y==0 only): input dots ioa[r]=A_row.iva, iob[r]=A_row.ivb.
template<int K, int N, int CPB, int MR>
__global__ __launch_bounds__((64 / MR) * (CPB / 8)) void gemm_rt(
    const float* __restrict__ A, const float* __restrict__ B,
    float* __restrict__ C, int M,
    const float* __restrict__ iva, const float* __restrict__ ivb,
    float* __restrict__ ioa, float* __restrict__ iob)
{
    constexpr int KC = 32;
    constexpr int NC = K / KC;
    constexpr int TC = CPB / 8;
    constexpr int TR = 64 / MR;
    constexpr int NT = TR * TC;
    constexpr int KT = KC / TC;
    constexpr int AST = 68;
    constexpr int A_F4 = 512 / NT;
    constexpr int B_F4 = (KC * CPB / 4) / NT;
    constexpr int MF = MR / 4;        // A float4 fragments per thread

    __shared__ float AsT[KC * AST];   // [k][row]
    __shared__ float Bs[KC * CPB];    // [k][col]

    const int tid = threadIdx.x;
    const int base = blockIdx.x * 64;
    const int col0 = blockIdx.y * CPB;
    const int tc = tid % TC;
    const int tr = tid / TC;

    float acc[MR][8];
#pragma unroll
    for (int m = 0; m < MR; ++m)
#pragma unroll
        for (int j = 0; j < 8; ++j) acc[m][j] = 0.f;
    float sa[MR], sb[MR];
#pragma unroll
    for (int m = 0; m < MR; ++m) { sa[m] = 0.f; sb[m] = 0.f; }

    float4 ra[A_F4], rb[B_F4];

    auto load_chunk = [&](int k0) {
#pragma unroll
        for (int j = 0; j < A_F4; ++j) {
            int i = tid + j * NT; int row = i >> 3; int q = i & 7;
            int gr = base + row;
            ra[j] = (gr < M) ? *(const float4*)(A + (size_t)gr * K + k0 + 4 * q)
                             : make_float4(0.f, 0.f, 0.f, 0.f);
        }
#pragma unroll
        for (int j = 0; j < B_F4; ++j) {
            int i = tid + j * NT; int kk_ = i / (CPB / 4); int c4 = i % (CPB / 4);
            rb[j] = *(const float4*)(B + (size_t)(k0 + kk_) * N + col0 + 4 * c4);
        }
    };
    auto write_chunk = [&]() {
#pragma unroll
        for (int j = 0; j < A_F4; ++j) {
            int i = tid + j * NT; int row = i >> 3; int q = i & 7;
            AsT[(4 * q + 0) * AST + row] = ra[j].x;
            AsT[(4 * q + 1) * AST + row] = ra[j].y;
            AsT[(4 * q + 2) * AST + row] = ra[j].z;
            AsT[(4 * q + 3) * AST + row] = ra[j].w;
        }
#pragma unroll
        for (int j = 0; j < B_F4; ++j) {
            int i = tid + j * NT; int kk_ = i / (CPB / 4); int c4 = i % (CPB / 4);
            *(float4*)(Bs + kk_ * CPB + 4 * c4) = rb[j];
        }
    };

    load_chunk(0);

    for (int ch = 0; ch < NC; ++ch) {
        write_chunk();
        __syncthreads();
        if (ch + 1 < NC) load_chunk((ch + 1) * KC);

#pragma unroll 8
        for (int kk = 0; kk < KC; ++kk) {
            const float* ap = AsT + kk * AST + MR * tr;
            const float* bp = Bs + kk * CPB + 8 * tc;
            float4 af[MF];
#pragma unroll
            for (int f = 0; f < MF; ++f) af[f] = *(const float4*)(ap + 4 * f);
            float4 b0 = *(const float4*)(bp);
            float4 b1 = *(const float4*)(bp + 4);
#pragma unroll
            for (int f = 0; f < MF; ++f) {
#pragma unroll
                for (int m = 0; m < 4; ++m) {
                    float av = ((const float*)&af[f])[m];
                    int mm = 4 * f + m;
                    acc[mm][0] = fmaf(av, b0.x, acc[mm][0]);
                    acc[mm][1] = fmaf(av, b0.y, acc[mm][1]);
                    acc[mm][2] = fmaf(av, b0.z, acc[mm][2]);
                    acc[mm][3] = fmaf(av, b0.w, acc[mm][3]);
                    acc[mm][4] = fmaf(av, b1.x, acc[mm][4]);
                    acc[mm][5] = fmaf(av, b1.y, acc[mm][5]);
                    acc[mm][6] = fmaf(av, b1.z, acc[mm][6]);
                    acc[mm][7] = fmaf(av, b1.w, acc[mm][7]);
                }
            }
        }

        if (iva != nullptr && blockIdx.y == 0) {
            const int k0 = ch * KC;
#pragma unroll
            for (int kl = 0; kl < KT; ++kl) {
                int k = tc * KT + kl;
                float av_ = iva[k0 + k];
                float bv_ = ivb[k0 + k];
#pragma unroll
                for (int m = 0; m < MR; ++m) {
                    float aval = AsT[k * AST + MR * tr + m];
                    sa[m] = fmaf(aval, av_, sa[m]);
                    sb[m] = fmaf(aval, bv_, sb[m]);
                }
            }
        }
        __syncthreads();
    }

#pragma unroll
    for (int m = 0; m < MR; ++m) {
        int gr = base + MR * tr + m;
        if (gr < M) {
            *(float4*)(C + (size_t)gr * N + col0 + 8 * tc) =
                make_float4(acc[m][0], acc[m][1], acc[m][2], acc[m][3]);
            *(float4*)(C + (size_t)gr * N + col0 + 8 * tc + 4) =
                make_float4(acc[m][4], acc[m][5], acc[m][6], acc[m][7]);
        }
    }
    if (iva != nullptr && blockIdx.y == 0) {
#pragma unroll
        for (int m = 0; m < MR; ++m) {
#pragma unroll
            for (int off = TC / 2; off; off >>= 1) {
                sa[m] += __shfl_xor(sa[m], off);
                sb[m] += __shfl_xor(sb[m], off);
            }
        }
        if (tc == 0) {
#pragma unroll
            for (int m = 0; m < MR; ++m) {
                int gr = base + MR * tr + m;
                if (gr < M) { ioa[gr] = sa[m]; iob[gr] = sb[m]; }
            }
        }
    }
}

// ---------------- small GEMM (final layer) ----------------
template<int K, int N, int NT>
__global__ __launch_bounds__(256) void gemm_tile(
    const float* __restrict__ A, const float* __restrict__ B,
    float* __restrict__ C, int M,
    const float* __restrict__ bias, const float* __restrict__ score, int outN)
{
    __shared__ float As[64 * K];
    const int tid = threadIdx.x;
    const int base = blockIdx.x * 64;
    for (int idx = tid; idx < 64 * K; idx += 256) {
        int r = idx / K, k = idx - r * K;
        int gr = base + r;
        As[idx] = (gr < M) ? A[(size_t)gr * K + k] : 0.f;
    }
    __syncthreads();
    constexpr int RSTEP = 256 / NT;
    constexpr int NR = 64 / RSTEP;
    const int c = tid % NT;
    const int r0 = tid / NT;
    float acc[NR];
#pragma unroll
    for (int i = 0; i < NR; ++i) acc[i] = 0.f;
    const float4* As4 = reinterpret_cast<const float4*>(As);
    const float* Bc = B + c;
    float b0 = Bc[0 * N], b1 = Bc[1 * N], b2 = Bc[2 * N], b3 = Bc[3 * N];
    for (int k = 0; k < K; k += 4) {
        const int kn = (k + 4 < K) ? (k + 4) : k;
        float n0 = Bc[(kn + 0) * N];
        float n1 = Bc[(kn + 1) * N];
        float n2 = Bc[(kn + 2) * N];
        float n3 = Bc[(kn + 3) * N];
#pragma unroll
        for (int i = 0; i < NR; ++i) {
            float4 a = As4[((r0 + i * RSTEP) * K + k) >> 2];
            acc[i] = fmaf(a.x, b0, acc[i]);
            acc[i] = fmaf(a.y, b1, acc[i]);
            acc[i] = fmaf(a.z, b2, acc[i]);
            acc[i] = fmaf(a.w, b3, acc[i]);
        }
        b0 = n0; b1 = n1; b2 = n2; b3 = n3;
    }
    if (c < outN) {
#pragma unroll
        for (int i = 0; i < NR; ++i) {
            int gr = base + r0 + i * RSTEP;
            if (gr < M) {
                float v = tanhf(score[gr]) * acc[i] + bias[c];
                C[(size_t)gr * outN + c] = fmaxf(v, 0.f);
            }
        }
    }
}

// ---------------- CSR build (ORIGINAL edges only; self-loops handled in-kernel) ----------------
__global__ __launch_bounds__(256) void hist_deg(
    const int* __restrict__ dst, int* __restrict__ deg, int E)
{
    int e = blockIdx.x * 256 + threadIdx.x;
    if (e < E) atomicAdd(deg + dst[e], 1);
}

__global__ __launch_bounds__(256) void scan_local(
    const int* __restrict__ deg, int* __restrict__ row_start, int* __restrict__ blocksum, int n)
{
    __shared__ int s[256];
    const int t = threadIdx.x;
    const int i = blockIdx.x * 256 + t;
    int v = (i < n) ? deg[i] : 0;
    s[t] = v;
    __syncthreads();
#pragma unroll
    for (int off = 1; off < 256; off <<= 1) {
        int u = (t >= off) ? s[t - off] : 0;
        __syncthreads();
        s[t] += u;
        __syncthreads();
    }
    if (i < n) row_start[i] = s[t] - v;
    if (t == 255) blocksum[blockIdx.x] = s[255];
}

__global__ __launch_bounds__(256) void scan_blocks(int* __restrict__ blocksum, int nb)
{
    __shared__ int s[256];
    const int t = threadIdx.x;
    int v = (t < nb) ? blocksum[t] : 0;
    s[t] = v;
    __syncthreads();
#pragma unroll
    for (int off = 1; off < 256; off <<= 1) {
        int u = (t >= off) ? s[t - off] : 0;
        __syncthreads();
        s[t] += u;
        __syncthreads();
    }
    if (t < nb) blocksum[t] = s[t] - v;
}

__global__ __launch_bounds__(256) void scan_add(
    int* __restrict__ row_start, int* __restrict__ cursor,
    const int* __restrict__ blocksum, int n, int total)
{
    const int i = blockIdx.x * 256 + threadIdx.x;
    if (i < n) {
        int v = row_start[i] + blocksum[blockIdx.x];
        row_start[i] = v;
        cursor[i] = v;
    } else if (i == n) {
        row_start[n] = total;
    }
}

__global__ __launch_bounds__(256) void fill_csr(
    const int* __restrict__ src, const int* __restrict__ dst,
    int* __restrict__ cursor, int* __restrict__ csr_src, int E)
{
    int e = blockIdx.x * 256 + threadIdx.x;
    if (e >= E) return;
    int pos = atomicAdd(cursor + dst[e], 1);
    csr_src[pos] = src[e];
}

// ---------------- fused GAT aggregation: one wave per node ----------------
// Merged exp+sum pass (no max subtraction; alpha bounded ~|2|). Self-loop
// handled in-register (CSR holds original edges only).
template<int D, bool POOL>
__global__ __launch_bounds__(256) void gat_aggregate(
    const int* __restrict__ row_start, const int* __restrict__ csr_src,
    const float* __restrict__ asv, const float* __restrict__ adv,
    const float* __restrict__ h, const float* __restrict__ bias,
    float* __restrict__ out,
    const float* __restrict__ wpr, const float* __restrict__ wpo,
    float* __restrict__ poolA, float* __restrict__ poolB, int n)
{
    __shared__ float lds_e[4][128];
    __shared__ int   lds_i[4][128];
    const int node = (blockIdx.x * 256 + threadIdx.x) >> 6;
    const int lane = threadIdx.x & 63;
    const int w = threadIdx.x >> 6;
    if (node >= n) return;
    const int beg = row_start[node];
    const int deg = row_start[node + 1] - beg;
    const float advv = adv[node];
    const bool fast = (deg <= 128);

    float a_self = asv[node] + advv;
    a_self = (a_self >= 0.f) ? a_self : 0.2f * a_self;
    const float ev_self = expf(a_self);

    float ssum = (lane == 0) ? ev_self : 0.f;
    if (fast) {
        for (int j = lane; j < deg; j += 64) {
            int s = csr_src[beg + j];
            lds_i[w][j] = s;
            float a = asv[s] + advv;
            a = (a >= 0.f) ? a : 0.2f * a;
            float ev = expf(a);
            lds_e[w][j] = ev;
            ssum += ev;
        }
    } else {
        for (int j = lane; j < deg; j += 64) {
            float a = asv[csr_src[beg + j]] + advv;
            a = (a >= 0.f) ? a : 0.2f * a;
            ssum += expf(a);
        }
    }
#pragma unroll
    for (int off = 32; off; off >>= 1) ssum += __shfl_xor(ssum, off);
    const float inv = 1.f / (ssum + 1e-16f);

    if (fast) {
        if constexpr (D == 128) {
            const float4* h4 = reinterpret_cast<const float4*>(h);
            const int half = lane >> 5;
            const int fl = lane & 31;
            float4 a0 = {0,0,0,0}, a1 = {0,0,0,0}, a2 = {0,0,0,0}, a3 = {0,0,0,0};
            int j = 0;
            for (; j + 8 <= deg; j += 8) {
                int e0 = j + half, e1 = j + 2 + half, e2 = j + 4 + half, e3 = j + 6 + half;
                int s0 = lds_i[w][e0], s1 = lds_i[w][e1], s2 = lds_i[w][e2], s3 = lds_i[w][e3];
                float c0 = lds_e[w][e0] * inv, c1 = lds_e[w][e1] * inv;
                float c2 = lds_e[w][e2] * inv, c3 = lds_e[w][e3] * inv;
                float4 v0 = h4[(size_t)s0 * 32 + fl];
                float4 v1 = h4[(size_t)s1 * 32 + fl];
                float4 v2 = h4[(size_t)s2 * 32 + fl];
                float4 v3 = h4[(size_t)s3 * 32 + fl];
                a0.x = fmaf(v0.x, c0, a0.x); a0.y = fmaf(v0.y, c0, a0.y);
                a0.z = fmaf(v0.z, c0, a0.z); a0.w = fmaf(v0.w, c0, a0.w);
                a1.x = fmaf(v1.x, c1, a1.x); a1.y = fmaf(v1.y, c1, a1.y);
                a1.z = fmaf(v1.z, c1, a1.z); a1.w = fmaf(v1.w, c1, a1.w);
                a2.x = fmaf(v2.x, c2, a2.x); a2.y = fmaf(v2.y, c2, a2.y);
                a2.z = fmaf(v2.z, c2, a2.z); a2.w = fmaf(v2.w, c2, a2.w);
                a3.x = fmaf(v3.x, c3, a3.x); a3.y = fmaf(v3.y, c3, a3.y);
                a3.z = fmaf(v3.z, c3, a3.z); a3.w = fmaf(v3.w, c3, a3.w);
            }
            for (; j < deg; j += 2) {
                int e = j + half;
                bool ok = (e < deg);
                int s = lds_i[w][ok ? e : 0];
                float c = ok ? lds_e[w][e] * inv : 0.f;
                float4 v = h4[(size_t)s * 32 + fl];
                a0.x = fmaf(v.x, c, a0.x); a0.y = fmaf(v.y, c, a0.y);
                a0.z = fmaf(v.z, c, a0.z); a0.w = fmaf(v.w, c, a0.w);
            }
            {   // self-loop (half 0 only)
                float c = (half == 0) ? ev_self * inv : 0.f;
                float4 v = h4[(size_t)node * 32 + fl];
                a1.x = fmaf(v.x, c, a1.x); a1.y = fmaf(v.y, c, a1.y);
                a1.z = fmaf(v.z, c, a1.z); a1.w = fmaf(v.w, c, a1.w);
            }
            float4 t;
            t.x = (a0.x + a1.x) + (a2.x + a3.x);
            t.y = (a0.y + a1.y) + (a2.y + a3.y);
            t.z = (a0.z + a1.z) + (a2.z + a3.z);
            t.w = (a0.w + a1.w) + (a2.w + a3.w);
            t.x += __shfl_xor(t.x, 32);
            t.y += __shfl_xor(t.y, 32);
            t.z += __shfl_xor(t.z, 32);
            t.w += __shfl_xor(t.w, 32);
            const float4 b4 = reinterpret_cast<const float4*>(bias)[fl];
            float4 o;
            o.x = fmaxf(t.x + b4.x, 0.f);
            o.y = fmaxf(t.y + b4.y, 0.f);
            o.z = fmaxf(t.z + b4.z, 0.f);
            o.w = fmaxf(t.w + b4.w, 0.f);
            if (half == 0)
                reinterpret_cast<float4*>(out)[(size_t)node * 32 + fl] = o;
            if constexpr (POOL) {
                const float4 r4 = reinterpret_cast<const float4*>(wpr)[fl];
                const float4 q4 = reinterpret_cast<const float4*>(wpo)[fl];
                float pa = o.x * r4.x + o.y * r4.y + o.z * r4.z + o.w * r4.w;
                float pb = o.x * q4.x + o.y * q4.y + o.z * q4.z + o.w * q4.w;
#pragma unroll
                for (int off = 16; off; off >>= 1) {
                    pa += __shfl_xor(pa, off);
                    pb += __shfl_xor(pb, off);
                }
                if (lane == 0) { poolA[node] = pa; poolB[node] = pb; }
            }
        } else {
            const float4* h4 = reinterpret_cast<const float4*>(h);
            const int q = lane >> 4;
            const int fl = lane & 15;
            float4 a0 = {0,0,0,0}, a1 = {0,0,0,0};
            int j = 0;
            for (; j + 8 <= deg; j += 8) {
                int e0 = j + q, e1 = j + 4 + q;
                int s0 = lds_i[w][e0], s1 = lds_i[w][e1];
                float c0 = lds_e[w][e0] * inv, c1 = lds_e[w][e1] * inv;
                float4 v0 = h4[(size_t)s0 * 16 + fl];
                float4 v1 = h4[(size_t)s1 * 16 + fl];
                a0.x = fmaf(v0.x, c0, a0.x); a0.y = fmaf(v0.y, c0, a0.y);
                a0.z = fmaf(v0.z, c0, a0.z); a0.w = fmaf(v0.w, c0, a0.w);
                a1.x = fmaf(v1.x, c1, a1.x); a1.y = fmaf(v1.y, c1, a1.y);
                a1.z = fmaf(v1.z, c1, a1.z); a1.w = fmaf(v1.w, c1, a1.w);
            }
            for (; j < deg; j += 4) {
                int e = j + q;
                bool ok = (e < deg);
                int s = lds_i[w][ok ? e : 0];
                float c = ok ? lds_e[w][e] * inv : 0.f;
                float4 v = h4[(size_t)s * 16 + fl];
                a0.x = fmaf(v.x, c, a0.x); a0.y = fmaf(v.y, c, a0.y);
                a0.z = fmaf(v.z, c, a0.z); a0.w = fmaf(v.w, c, a0.w);
            }
            {   // self-loop (q 0 only)
                float c = (q == 0) ? ev_self * inv : 0.f;
                float4 v = h4[(size_t)node * 16 + fl];
                a1.x = fmaf(v.x, c, a1.x); a1.y = fmaf(v.y, c, a1.y);
                a1.z = fmaf(v.z, c, a1.z); a1.w = fmaf(v.w, c, a1.w);
            }
            float4 t;
            t.x = a0.x + a1.x; t.y = a0.y + a1.y; t.z = a0.z + a1.z; t.w = a0.w + a1.w;
            t.x += __shfl_xor(t.x, 16); t.x += __shfl_xor(t.x, 32);
            t.y += __shfl_xor(t.y, 16); t.y += __shfl_xor(t.y, 32);
            t.z += __shfl_xor(t.z, 16); t.z += __shfl_xor(t.z, 32);
            t.w += __shfl_xor(t.w, 16); t.w += __shfl_xor(t.w, 32);
            const float4 b4 = reinterpret_cast<const float4*>(bias)[fl];
            float4 o;
            o.x = fmaxf(t.x + b4.x, 0.f);
            o.y = fmaxf(t.y + b4.y, 0.f);
            o.z = fmaxf(t.z + b4.z, 0.f);
            o.w = fmaxf(t.w + b4.w, 0.f);
            if (q == 0)
                reinterpret_cast<float4*>(out)[(size_t)node * 16 + fl] = o;
        }
    } else {
        // slow path (deg > 128): recompute exp per edge
        if constexpr (D == 128) {
            const float2* h2 = reinterpret_cast<const float2*>(h);
            float2 a0 = {0.f, 0.f};
            for (int j = 0; j < deg; ++j) {
                int s = csr_src[beg + j];
                float a = asv[s] + advv;
                a = (a >= 0.f) ? a : 0.2f * a;
                float c = expf(a) * inv;
                float2 v = h2[(size_t)s * 64 + lane];
                a0.x = fmaf(v.x, c, a0.x); a0.y = fmaf(v.y, c, a0.y);
            }
            {
                float c = ev_self * inv;
                float2 v = h2[(size_t)node * 64 + lane];
                a0.x = fmaf(v.x, c, a0.x); a0.y = fmaf(v.y, c, a0.y);
            }
            float2 o;
            o.x = fmaxf(a0.x + bias[2 * lane], 0.f);
            o.y = fmaxf(a0.y + bias[2 * lane + 1], 0.f);
            reinterpret_cast<float2*>(out)[(size_t)node * 64 + lane] = o;
            if constexpr (POOL) {
                float pa = fmaf(o.x, wpr[2 * lane], o.y * wpr[2 * lane + 1]);
                float pb = fmaf(o.x, wpo[2 * lane], o.y * wpo[2 * lane + 1]);
#pragma unroll
                for (int off = 32; off; off >>= 1) {
                    pa += __shfl_xor(pa, off);
                    pb += __shfl_xor(pb, off);
                }
                if (lane == 0) { poolA[node] = pa; poolB[node] = pb; }
            }
        } else {
            float a0 = 0.f;
            for (int j = 0; j < deg; ++j) {
                int s = csr_src[beg + j];
                float a = asv[s] + advv;
                a = (a >= 0.f) ? a : 0.2f * a;
                a0 = fmaf(h[(size_t)s * D + lane], expf(a) * inv, a0);
            }
            a0 = fmaf(h[(size_t)node * D + lane], ev_self * inv, a0);
            out[(size_t)node * D + lane] = fmaxf(a0 + bias[lane], 0.f);
        }
    }
}

// ---------------- pooling score via CSR (original edges; no self-loops) ----------------
__global__ __launch_bounds__(256) void score_csr(
    const int* __restrict__ row_start, const int* __restrict__ csr_src,
    const float* __restrict__ ts, const float* __restrict__ td,
    const float* __restrict__ bp, float* __restrict__ score, int n)
{
    int i = blockIdx.x * 256 + threadIdx.x;
    if (i >= n) return;
    int beg = row_start[i], end = row_start[i + 1];
    float s = td[i] + bp[0];
    for (int j = beg; j < end; ++j) s += ts[csr_src[j]];
    score[i] = s;
}

// ---------------- precompute: va_l = W_l @ a; pad Wl/bl; zero deg ----------------
__global__ __launch_bounds__(256) void precompute(
    const float* __restrict__ W1, const float* __restrict__ a1s, const float* __restrict__ a1d,
    const float* __restrict__ W2, const float* __restrict__ a2s, const float* __restrict__ a2d,
    const float* __restrict__ W3, const float* __restrict__ a3s, const float* __restrict__ a3d,
    const float* __restrict__ Wl, const float* __restrict__ bl,
    float* __restrict__ va1, float* __restrict__ vb1,
    float* __restrict__ va2, float* __restrict__ vb2,
    float* __restrict__ va3, float* __restrict__ vb3,
    float* __restrict__ Wlp, float* __restrict__ blp,
    int* __restrict__ deg, int n)
{
    int t = blockIdx.x * 256 + threadIdx.x;
    if (t < n) deg[t] = 0;
    if (t < 128) {
        float sa = 0.f, sb = 0.f;
        for (int j = 0; j < 64; ++j) {
            float w = W1[t * 64 + j];
            sa = fmaf(w, a1s[j], sa); sb = fmaf(w, a1d[j], sb);
        }
        va1[t] = sa; vb1[t] = sb;
    } else if (t < 192) {
        int k = t - 128;
        float sa = 0.f, sb = 0.f;
        for (int j = 0; j < 128; ++j) {
            float w = W2[k * 128 + j];
            sa = fmaf(w, a2s[j], sa); sb = fmaf(w, a2d[j], sb);
        }
        va2[k] = sa; vb2[k] = sb;
    } else if (t < 320) {
        int k = t - 192;
        float sa = 0.f, sb = 0.f;
        for (int j = 0; j < 128; ++j) {
            float w = W3[k * 128 + j];
            sa = fmaf(w, a3s[j], sa); sb = fmaf(w, a3d[j], sb);
        }
        va3[k] = sa; vb3[k] = sb;
    } else if (t < 320 + 2048) {
        int i = t - 320;
        int k = i >> 4, c = i & 15;
        Wlp[i] = (c < 10) ? Wl[k * 10 + c] : 0.f;
    } else if (t < 320 + 2048 + 16) {
        int c = t - (320 + 2048);
        blp[c] = (c < 10) ? bl[c] : 0.f;
    }
}

extern "C" void kernel_launch(void* const* d_in, const int* in_sizes, int n_in,
                              void* d_out, int out_size, void* d_ws, size_t ws_size,
                              hipStream_t stream) {
    const float* x   = (const float*)d_in[0];
    const int*   ei  = (const int*)d_in[1];
    const float* W1  = (const float*)d_in[4];
    const float* a1s = (const float*)d_in[5];
    const float* a1d = (const float*)d_in[6];
    const float* b1  = (const float*)d_in[7];
    const float* W2  = (const float*)d_in[8];
    const float* a2s = (const float*)d_in[9];
    const float* a2d = (const float*)d_in[10];
    const float* b2  = (const float*)d_in[11];
    const float* W3  = (const float*)d_in[12];
    const float* a3s = (const float*)d_in[13];
    const float* a3d = (const float*)d_in[14];
    const float* b3  = (const float*)d_in[15];
    const float* wpr = (const float*)d_in[16];
    const float* wpo = (const float*)d_in[17];
    const float* bp  = (const float*)d_in[18];
    const float* Wl  = (const float*)d_in[19];
    const float* bl  = (const float*)d_in[20];

    const int n = in_sizes[0] / 128;   // 40000
    const int E = in_sizes[1] / 2;     // 640000
    const int* src = ei;
    const int* dst = ei + E;

    float* ws = (float*)d_ws;
    const size_t nd = (size_t)n * 128;
    float* bufA      = ws;                          // [n,128]
    float* bufB      = bufA + nd;                   // [n,128]
    float* asv       = bufB + nd;                   // [n]
    float* adv       = asv + n;                     // [n]
    float* tsv       = adv + n;                     // [n]
    float* tdv       = tsv + n;                     // [n]
    float* score     = tdv + n;                     // [n]
    int*   deg       = (int*)(score + n);           // [n]
    int*   row_start = deg + n;                     // [n+1]
    int*   cursor    = row_start + n + 1;           // [n]
    int*   blocksum  = cursor + n;                  // [<=256]
    int*   csr_src   = blocksum + 256;              // [E]
    float* va1       = (float*)(csr_src + E);       // [128]
    float* vb1       = va1 + 128;                   // [128]
    float* va2       = vb1 + 128;                   // [64]
    float* vb2       = va2 + 64;                    // [64]
    float* va3       = vb2 + 64;                    // [128]
    float* vb3       = va3 + 128;                   // [128]
    float* Wlp       = vb3 + 128;                   // [128*16]
    float* blp       = Wlp + 128 * 16;              // [16]

    const unsigned EB = (unsigned)((E + 255) / 256);
    const unsigned NB = (unsigned)((n + 255) / 256);
    const unsigned MB = (unsigned)((n + 63) / 64);   // 625
    const unsigned WB = (unsigned)(((size_t)n * 64 + 255) / 256);

    // ---------- precompute (+deg zero) + CSR build ----------
    precompute<<<NB, 256, 0, stream>>>(W1, a1s, a1d, W2, a2s, a2d, W3, a3s, a3d, Wl, bl,
                                       va1, vb1, va2, vb2, va3, vb3, Wlp, blp, deg, n);
    hist_deg<<<EB, 256, 0, stream>>>(dst, deg, E);
    scan_local<<<NB, 256, 0, stream>>>(deg, row_start, blocksum, n);
    scan_blocks<<<1, 256, 0, stream>>>(blocksum, (int)NB);
    scan_add<<<NB, 256, 0, stream>>>(row_start, cursor, blocksum, n, E);
    fill_csr<<<EB, 256, 0, stream>>>(src, dst, cursor, csr_src, E);

    // ---------- Layer 1: 128 -> 64 (MR=4, 128 thr, proven config) ----------
    gemm_rt<128, 64, 64, 4><<<dim3(MB, 1), 128, 0, stream>>>(
        x, W1, bufA, n, va1, vb1, asv, adv);
    gat_aggregate<64, false><<<WB, 256, 0, stream>>>(row_start, csr_src, asv, adv, bufA, b1, bufB,
                                                     nullptr, nullptr, nullptr, nullptr, n);

    // ---------- Layer 2: 64 -> 128 (MR=8, full-N, 128 thr) ----------
    gemm_rt<64, 128, 128, 8><<<dim3(MB, 1), 128, 0, stream>>>(
        bufB, W2, bufA, n, va2, vb2, asv, adv);
    gat_aggregate<128, false><<<WB, 256, 0, stream>>>(row_start, csr_src, asv, adv, bufA, b2, bufB,
                                                      nullptr, nullptr, nullptr, nullptr, n);

    // ---------- Layer 3: 128 -> 128 (MR=8, full-N, 128 thr) ----------
    gemm_rt<128, 128, 128, 8><<<dim3(MB, 1), 128, 0, stream>>>(
        bufB, W3, bufA, n, va3, vb3, asv, adv);
    gat_aggregate<128, true><<<WB, 256, 0, stream>>>(row_start, csr_src, asv, adv, bufA, b3, bufB,
                                                     wpr, wpo, tsv, tdv, n);

    // ---------- SAGPool score + final linear ----------
    score_csr<<<NB, 256, 0, stream>>>(row_start, csr_src, tsv, tdv, bp, score, n);
    gemm_tile<128, 16, 16><<<MB, 256, 0, stream>>>(bufB, Wlp, (float*)d_out, n, blp, score, 10);
}

// Round 14
// 296.601 us; speedup vs baseline: 1.0590x; 1.0590x over previous
//
#include <hip/hip_runtime.h>
#include <math.h>

// ---------------- register-tiled GEMM: C[M,N] = A[M,K] @ B[K,N] ----------------
// BM=64 rows/block, CPB cols/block (gridDim.y = N/CPB). 2*CPB threads,
// per-thread MR=4 rows x 8 cols. Reg->LDS staging, next chunk prefetched
// into registers right after the barrier (lands under the math).
// iva != nullptr (y==0 only): input dots ioa[r]=A_row.iva, iob[r]=A_row.ivb.
template<int K, int N, int CPB>
__global__ __launch_bounds__(2 * CPB) void gemm_rt(
    const float* __restrict__ A, const float* __restrict__ B,
    float* __restrict__ C, int M,
    const float* __restrict__ iva, const float* __restrict__ ivb,
    float* __restrict__ ioa, float* __restrict__ iob)
{
    constexpr int KC = 32;
    constexpr int NC = K / KC;
    constexpr int TC = CPB / 8;
    constexpr int NT = 2 * CPB;
    constexpr int KT = KC / TC;
    constexpr int AST = 68;
    constexpr int A_F4 = 512 / NT;
    constexpr int B_F4 = (KC * CPB / 4) / NT;

    __shared__ float AsT[KC * AST];
    __shared__ float Bs[KC * CPB];

    const int tid = threadIdx.x;
    const int base = blockIdx.x * 64;
    const int col0 = blockIdx.y * CPB;
    const int tc = tid % TC;
    const int tr = tid / TC;

    float acc[4][8];
#pragma unroll
    for (int m = 0; m < 4; ++m)
#pragma unroll
        for (int j = 0; j < 8; ++j) acc[m][j] = 0.f;
    float sa[4], sb[4];
#pragma unroll
    for (int m = 0; m < 4; ++m) { sa[m] = 0.f; sb[m] = 0.f; }

    float4 ra[A_F4], rb[B_F4];

#pragma unroll
    for (int j = 0; j < A_F4; ++j) {
        int i = tid + j * NT; int row = i >> 3; int q = i & 7;
        int gr = base + row;
        ra[j] = (gr < M) ? *(const float4*)(A + (size_t)gr * K + 4 * q)
                         : make_float4(0.f, 0.f, 0.f, 0.f);
    }
#pragma unroll
    for (int j = 0; j < B_F4; ++j) {
        int i = tid + j * NT; int kk_ = i / (CPB / 4); int c4 = i % (CPB / 4);
        rb[j] = *(const float4*)(B + (size_t)kk_ * N + col0 + 4 * c4);
    }

    for (int ch = 0; ch < NC; ++ch) {
#pragma unroll
        for (int j = 0; j < A_F4; ++j) {
            int i = tid + j * NT; int row = i >> 3; int q = i & 7;
            AsT[(4 * q + 0) * AST + row] = ra[j].x;
            AsT[(4 * q + 1) * AST + row] = ra[j].y;
            AsT[(4 * q + 2) * AST + row] = ra[j].z;
            AsT[(4 * q + 3) * AST + row] = ra[j].w;
        }
#pragma unroll
        for (int j = 0; j < B_F4; ++j) {
            int i = tid + j * NT; int kk_ = i / (CPB / 4); int c4 = i % (CPB / 4);
            *(float4*)(Bs + kk_ * CPB + 4 * c4) = rb[j];
        }
        __syncthreads();

        if (ch + 1 < NC) {
            const int k0 = (ch + 1) * KC;
#pragma unroll
            for (int j = 0; j < A_F4; ++j) {
                int i = tid + j * NT; int row = i >> 3; int q = i & 7;
                int gr = base + row;
                ra[j] = (gr < M) ? *(const float4*)(A + (size_t)gr * K + k0 + 4 * q)
                                 : make_float4(0.f, 0.f, 0.f, 0.f);
            }
#pragma unroll
            for (int j = 0; j < B_F4; ++j) {
                int i = tid + j * NT; int kk_ = i / (CPB / 4); int c4 = i % (CPB / 4);
                rb[j] = *(const float4*)(B + (size_t)(k0 + kk_) * N + col0 + 4 * c4);
            }
        }

#pragma unroll 8
        for (int kk = 0; kk < KC; ++kk) {
            float4 a0 = *(const float4*)(AsT + kk * AST + 4 * tr);
            const float* bp = Bs + kk * CPB + 8 * tc;
            float4 b0 = *(const float4*)(bp);
            float4 b1 = *(const float4*)(bp + 4);
#pragma unroll
            for (int m = 0; m < 4; ++m) {
                float av = ((const float*)&a0)[m];
                acc[m][0] = fmaf(av, b0.x, acc[m][0]);
                acc[m][1] = fmaf(av, b0.y, acc[m][1]);
                acc[m][2] = fmaf(av, b0.z, acc[m][2]);
                acc[m][3] = fmaf(av, b0.w, acc[m][3]);
                acc[m][4] = fmaf(av, b1.x, acc[m][4]);
                acc[m][5] = fmaf(av, b1.y, acc[m][5]);
                acc[m][6] = fmaf(av, b1.z, acc[m][6]);
                acc[m][7] = fmaf(av, b1.w, acc[m][7]);
            }
        }

        if (iva != nullptr && blockIdx.y == 0) {
            const int k0 = ch * KC;
#pragma unroll
            for (int kl = 0; kl < KT; ++kl) {
                int k = tc * KT + kl;
                float av_ = iva[k0 + k];
                float bv_ = ivb[k0 + k];
#pragma unroll
                for (int m = 0; m < 4; ++m) {
                    float aval = AsT[k * AST + 4 * tr + m];
                    sa[m] = fmaf(aval, av_, sa[m]);
                    sb[m] = fmaf(aval, bv_, sb[m]);
                }
            }
        }
        __syncthreads();
    }

#pragma unroll
    for (int m = 0; m < 4; ++m) {
        int gr = base + 4 * tr + m;
        if (gr < M) {
            *(float4*)(C + (size_t)gr * N + col0 + 8 * tc) =
                make_float4(acc[m][0], acc[m][1], acc[m][2], acc[m][3]);
            *(float4*)(C + (size_t)gr * N + col0 + 8 * tc + 4) =
                make_float4(acc[m][4], acc[m][5], acc[m][6], acc[m][7]);
        }
    }
    if (iva != nullptr && blockIdx.y == 0) {
#pragma unroll
        for (int m = 0; m < 4; ++m) {
#pragma unroll
            for (int off = TC / 2; off; off >>= 1) {
                sa[m] += __shfl_xor(sa[m], off);
                sb[m] += __shfl_xor(sb[m], off);
            }
        }
        if (tc == 0) {
#pragma unroll
            for (int m = 0; m < 4; ++m) {
                int gr = base + 4 * tr + m;
                if (gr < M) { ioa[gr] = sa[m]; iob[gr] = sb[m]; }
            }
        }
    }
}

// ---------------- small GEMM (final layer) ----------------
template<int K, int N, int NT>
__global__ __launch_bounds__(256) void gemm_tile(
    const float* __restrict__ A, const float* __restrict__ B,
    float* __restrict__ C, int M,
    const float* __restrict__ bias, const float* __restrict__ score, int outN)
{
    __shared__ float As[64 * K];
    const int tid = threadIdx.x;
    const int base = blockIdx.x * 64;
    for (int idx = tid; idx < 64 * K; idx += 256) {
        int r = idx / K, k = idx - r * K;
        int gr = base + r;
        As[idx] = (gr < M) ? A[(size_t)gr * K + k] : 0.f;
    }
    __syncthreads();
    constexpr int RSTEP = 256 / NT;
    constexpr int NR = 64 / RSTEP;
    const int c = tid % NT;
    const int r0 = tid / NT;
    float acc[NR];
#pragma unroll
    for (int i = 0; i < NR; ++i) acc[i] = 0.f;
    const float4* As4 = reinterpret_cast<const float4*>(As);
    const float* Bc = B + c;
    float b0 = Bc[0 * N], b1 = Bc[1 * N], b2 = Bc[2 * N], b3 = Bc[3 * N];
    for (int k = 0; k < K; k += 4) {
        const int kn = (k + 4 < K) ? (k + 4) : k;
        float n0 = Bc[(kn + 0) * N];
        float n1 = Bc[(kn + 1) * N];
        float n2 = Bc[(kn + 2) * N];
        float n3 = Bc[(kn + 3) * N];
#pragma unroll
        for (int i = 0; i < NR; ++i) {
            float4 a = As4[((r0 + i * RSTEP) * K + k) >> 2];
            acc[i] = fmaf(a.x, b0, acc[i]);
            acc[i] = fmaf(a.y, b1, acc[i]);
            acc[i] = fmaf(a.z, b2, acc[i]);
            acc[i] = fmaf(a.w, b3, acc[i]);
        }
        b0 = n0; b1 = n1; b2 = n2; b3 = n3;
    }
    if (c < outN) {
#pragma unroll
        for (int i = 0; i < NR; ++i) {
            int gr = base + r0 + i * RSTEP;
            if (gr < M) {
                float v = tanhf(score[gr]) * acc[i] + bias[c];
                C[(size_t)gr * outN + c] = fmaxf(v, 0.f);
            }
        }
    }
}

// ---------------- CSR build (ORIGINAL edges only; self-loops handled in-kernel) ----------------
__global__ __launch_bounds__(256) void hist_deg(
    const int* __restrict__ dst, int* __restrict__ deg, int E)
{
    int e = blockIdx.x * 256 + threadIdx.x;
    if (e < E) atomicAdd(deg + dst[e], 1);
}

__global__ __launch_bounds__(256) void scan_local(
    const int* __restrict__ deg, int* __restrict__ row_start, int* __restrict__ blocksum, int n)
{
    __shared__ int s[256];
    const int t = threadIdx.x;
    const int i = blockIdx.x * 256 + t;
    int v = (i < n) ? deg[i] : 0;
    s[t] = v;
    __syncthreads();
#pragma unroll
    for (int off = 1; off < 256; off <<= 1) {
        int u = (t >= off) ? s[t - off] : 0;
        __syncthreads();
        s[t] += u;
        __syncthreads();
    }
    if (i < n) row_start[i] = s[t] - v;
    if (t == 255) blocksum[blockIdx.x] = s[255];
}

__global__ __launch_bounds__(256) void scan_blocks(int* __restrict__ blocksum, int nb)
{
    __shared__ int s[256];
    const int t = threadIdx.x;
    int v = (t < nb) ? blocksum[t] : 0;
    s[t] = v;
    __syncthreads();
#pragma unroll
    for (int off = 1; off < 256; off <<= 1) {
        int u = (t >= off) ? s[t - off] : 0;
        __syncthreads();
        s[t] += u;
        __syncthreads();
    }
    if (t < nb) blocksum[t] = s[t] - v;
}

__global__ __launch_bounds__(256) void scan_add(
    int* __restrict__ row_start, int* __restrict__ cursor,
    const int* __restrict__ blocksum, int n, int total)
{
    const int i = blockIdx.x * 256 + threadIdx.x;
    if (i < n) {
        int v = row_start[i] + blocksum[blockIdx.x];
        row_start[i] = v;
        cursor[i] = v;
    } else if (i == n) {
        row_start[n] = total;
    }
}

__global__ __launch_bounds__(256) void fill_csr(
    const int* __restrict__ src, const int* __restrict__ dst,
    int* __restrict__ cursor, int* __restrict__ csr_src, int E)
{
    int e = blockIdx.x * 256 + threadIdx.x;
    if (e >= E) return;
    int pos = atomicAdd(cursor + dst[e], 1);
    csr_src[pos] = src[e];
}

// ---------------- fused GAT aggregation: one wave per node ----------------
// Merged exp+sum pass (no max subtraction: coef = exp(a)/Sum exp(a), exact in
// real arithmetic since exp(a-m)/Sum exp(a-m) cancels m; alpha bounded ~|2|).
// Self-loop handled in-register (CSR holds original edges only).
template<int D, bool POOL>
__global__ __launch_bounds__(256) void gat_aggregate(
    const int* __restrict__ row_start, const int* __restrict__ csr_src,
    const float* __restrict__ asv, const float* __restrict__ adv,
    const float* __restrict__ h, const float* __restrict__ bias,
    float* __restrict__ out,
    const float* __restrict__ wpr, const float* __restrict__ wpo,
    float* __restrict__ poolA, float* __restrict__ poolB, int n)
{
    __shared__ float lds_e[4][128];
    __shared__ int   lds_i[4][128];
    const int node = (blockIdx.x * 256 + threadIdx.x) >> 6;
    const int lane = threadIdx.x & 63;
    const int w = threadIdx.x >> 6;
    if (node >= n) return;
    const int beg = row_start[node];
    const int deg = row_start[node + 1] - beg;
    const float advv = adv[node];
    const bool fast = (deg <= 128);

    float a_self = asv[node] + advv;
    a_self = (a_self >= 0.f) ? a_self : 0.2f * a_self;
    const float ev_self = expf(a_self);

    float ssum = (lane == 0) ? ev_self : 0.f;
    if (fast) {
        for (int j = lane; j < deg; j += 64) {
            int s = csr_src[beg + j];
            lds_i[w][j] = s;
            float a = asv[s] + advv;
            a = (a >= 0.f) ? a : 0.2f * a;
            float ev = expf(a);
            lds_e[w][j] = ev;
            ssum += ev;
        }
    } else {
        for (int j = lane; j < deg; j += 64) {
            float a = asv[csr_src[beg + j]] + advv;
            a = (a >= 0.f) ? a : 0.2f * a;
            ssum += expf(a);
        }
    }
#pragma unroll
    for (int off = 32; off; off >>= 1) ssum += __shfl_xor(ssum, off);
    const float inv = 1.f / (ssum + 1e-16f);

    if (fast) {
        if constexpr (D == 128) {
            const float4* h4 = reinterpret_cast<const float4*>(h);
            const int half = lane >> 5;
            const int fl = lane & 31;
            float4 a0 = {0,0,0,0}, a1 = {0,0,0,0}, a2 = {0,0,0,0}, a3 = {0,0,0,0};
            int j = 0;
            for (; j + 8 <= deg; j += 8) {
                int e0 = j + half, e1 = j + 2 + half, e2 = j + 4 + half, e3 = j + 6 + half;
                int s0 = lds_i[w][e0], s1 = lds_i[w][e1], s2 = lds_i[w][e2], s3 = lds_i[w][e3];
                float c0 = lds_e[w][e0] * inv, c1 = lds_e[w][e1] * inv;
                float c2 = lds_e[w][e2] * inv, c3 = lds_e[w][e3] * inv;
                float4 v0 = h4[(size_t)s0 * 32 + fl];
                float4 v1 = h4[(size_t)s1 * 32 + fl];
                float4 v2 = h4[(size_t)s2 * 32 + fl];
                float4 v3 = h4[(size_t)s3 * 32 + fl];
                a0.x = fmaf(v0.x, c0, a0.x); a0.y = fmaf(v0.y, c0, a0.y);
                a0.z = fmaf(v0.z, c0, a0.z); a0.w = fmaf(v0.w, c0, a0.w);
                a1.x = fmaf(v1.x, c1, a1.x); a1.y = fmaf(v1.y, c1, a1.y);
                a1.z = fmaf(v1.z, c1, a1.z); a1.w = fmaf(v1.w, c1, a1.w);
                a2.x = fmaf(v2.x, c2, a2.x); a2.y = fmaf(v2.y, c2, a2.y);
                a2.z = fmaf(v2.z, c2, a2.z); a2.w = fmaf(v2.w, c2, a2.w);
                a3.x = fmaf(v3.x, c3, a3.x); a3.y = fmaf(v3.y, c3, a3.y);
                a3.z = fmaf(v3.z, c3, a3.z); a3.w = fmaf(v3.w, c3, a3.w);
            }
            for (; j < deg; j += 2) {
                int e = j + half;
                bool ok = (e < deg);
                int s = lds_i[w][ok ? e : 0];
                float c = ok ? lds_e[w][e] * inv : 0.f;
                float4 v = h4[(size_t)s * 32 + fl];
                a0.x = fmaf(v.x, c, a0.x); a0.y = fmaf(v.y, c, a0.y);
                a0.z = fmaf(v.z, c, a0.z); a0.w = fmaf(v.w, c, a0.w);
            }
            {   // self-loop (half 0 only; counted once)
                float c = (half == 0) ? ev_self * inv : 0.f;
                float4 v = h4[(size_t)node * 32 + fl];
                a1.x = fmaf(v.x, c, a1.x); a1.y = fmaf(v.y, c, a1.y);
                a1.z = fmaf(v.z, c, a1.z); a1.w = fmaf(v.w, c, a1.w);
            }
            float4 t;
            t.x = (a0.x + a1.x) + (a2.x + a3.x);
            t.y = (a0.y + a1.y) + (a2.y + a3.y);
            t.z = (a0.z + a1.z) + (a2.z + a3.z);
            t.w = (a0.w + a1.w) + (a2.w + a3.w);
            t.x += __shfl_xor(t.x, 32);
            t.y += __shfl_xor(t.y, 32);
            t.z += __shfl_xor(t.z, 32);
            t.w += __shfl_xor(t.w, 32);
            const float4 b4 = reinterpret_cast<const float4*>(bias)[fl];
            float4 o;
            o.x = fmaxf(t.x + b4.x, 0.f);
            o.y = fmaxf(t.y + b4.y, 0.f);
            o.z = fmaxf(t.z + b4.z, 0.f);
            o.w = fmaxf(t.w + b4.w, 0.f);
            if (half == 0)
                reinterpret_cast<float4*>(out)[(size_t)node * 32 + fl] = o;
            if constexpr (POOL) {
                const float4 r4 = reinterpret_cast<const float4*>(wpr)[fl];
                const float4 q4 = reinterpret_cast<const float4*>(wpo)[fl];
                float pa = o.x * r4.x + o.y * r4.y + o.z * r4.z + o.w * r4.w;
                float pb = o.x * q4.x + o.y * q4.y + o.z * q4.z + o.w * q4.w;
#pragma unroll
                for (int off = 16; off; off >>= 1) {
                    pa += __shfl_xor(pa, off);
                    pb += __shfl_xor(pb, off);
                }
                if (lane == 0) { poolA[node] = pa; poolB[node] = pb; }
            }
        } else {
            const float4* h4 = reinterpret_cast<const float4*>(h);
            const int q = lane >> 4;
            const int fl = lane & 15;
            float4 a0 = {0,0,0,0}, a1 = {0,0,0,0};
            int j = 0;
            for (; j + 8 <= deg; j += 8) {
                int e0 = j + q, e1 = j + 4 + q;
                int s0 = lds_i[w][e0], s1 = lds_i[w][e1];
                float c0 = lds_e[w][e0] * inv, c1 = lds_e[w][e1] * inv;
                float4 v0 = h4[(size_t)s0 * 16 + fl];
                float4 v1 = h4[(size_t)s1 * 16 + fl];
                a0.x = fmaf(v0.x, c0, a0.x); a0.y = fmaf(v0.y, c0, a0.y);
                a0.z = fmaf(v0.z, c0, a0.z); a0.w = fmaf(v0.w, c0, a0.w);
                a1.x = fmaf(v1.x, c1, a1.x); a1.y = fmaf(v1.y, c1, a1.y);
                a1.z = fmaf(v1.z, c1, a1.z); a1.w = fmaf(v1.w, c1, a1.w);
            }
            for (; j < deg; j += 4) {
                int e = j + q;
                bool ok = (e < deg);
                int s = lds_i[w][ok ? e : 0];
                float c = ok ? lds_e[w][e] * inv : 0.f;
                float4 v = h4[(size_t)s * 16 + fl];
                a0.x = fmaf(v.x, c, a0.x); a0.y = fmaf(v.y, c, a0.y);
                a0.z = fmaf(v.z, c, a0.z); a0.w = fmaf(v.w, c, a0.w);
            }
            {   // self-loop (q 0 only)
                float c = (q == 0) ? ev_self * inv : 0.f;
                float4 v = h4[(size_t)node * 16 + fl];
                a1.x = fmaf(v.x, c, a1.x); a1.y = fmaf(v.y, c, a1.y);
                a1.z = fmaf(v.z, c, a1.z); a1.w = fmaf(v.w, c, a1.w);
            }
            float4 t;
            t.x = a0.x + a1.x; t.y = a0.y + a1.y; t.z = a0.z + a1.z; t.w = a0.w + a1.w;
            t.x += __shfl_xor(t.x, 16); t.x += __shfl_xor(t.x, 32);
            t.y += __shfl_xor(t.y, 16); t.y += __shfl_xor(t.y, 32);
            t.z += __shfl_xor(t.z, 16); t.z += __shfl_xor(t.z, 32);
            t.w += __shfl_xor(t.w, 16); t.w += __shfl_xor(t.w, 32);
            const float4 b4 = reinterpret_cast<const float4*>(bias)[fl];
            float4 o;
            o.x = fmaxf(t.x + b4.x, 0.f);
            o.y = fmaxf(t.y + b4.y, 0.f);
            o.z = fmaxf(t.z + b4.z, 0.f);
            o.w = fmaxf(t.w + b4.w, 0.f);
            if (q == 0)
                reinterpret_cast<float4*>(out)[(size_t)node * 16 + fl] = o;
        }
    } else {
        // slow path (deg > 128): recompute exp per edge
        if constexpr (D == 128) {
            const float2* h2 = reinterpret_cast<const float2*>(h);
            float2 a0 = {0.f, 0.f};
            for (int j = 0; j < deg; ++j) {
                int s = csr_src[beg + j];
                float a = asv[s] + advv;
                a = (a >= 0.f) ? a : 0.2f * a;
                float c = expf(a) * inv;
                float2 v = h2[(size_t)s * 64 + lane];
                a0.x = fmaf(v.x, c, a0.x); a0.y = fmaf(v.y, c, a0.y);
            }
            {
                float c = ev_self * inv;
                float2 v = h2[(size_t)node * 64 + lane];
                a0.x = fmaf(v.x, c, a0.x); a0.y = fmaf(v.y, c, a0.y);
            }
            float2 o;
            o.x = fmaxf(a0.x + bias[2 * lane], 0.f);
            o.y = fmaxf(a0.y + bias[2 * lane + 1], 0.f);
            reinterpret_cast<float2*>(out)[(size_t)node * 64 + lane] = o;
            if constexpr (POOL) {
                float pa = fmaf(o.x, wpr[2 * lane], o.y * wpr[2 * lane + 1]);
                float pb = fmaf(o.x, wpo[2 * lane], o.y * wpo[2 * lane + 1]);
#pragma unroll
                for (int off = 32; off; off >>= 1) {
                    pa += __shfl_xor(pa, off);
                    pb += __shfl_xor(pb, off);
                }
                if (lane == 0) { poolA[node] = pa; poolB[node] = pb; }
            }
        } else {
            float a0 = 0.f;
            for (int j = 0; j < deg; ++j) {
                int s = csr_src[beg + j];
                float a = asv[s] + advv;
                a = (a >= 0.f) ? a : 0.2f * a;
                a0 = fmaf(h[(size_t)s * D + lane], expf(a) * inv, a0);
            }
            a0 = fmaf(h[(size_t)node * D + lane], ev_self * inv, a0);
            out[(size_t)node * D + lane] = fmaxf(a0 + bias[lane], 0.f);
        }
    }
}

// ---------------- pooling score via CSR (original edges; no self-loops here) ----------------
__global__ __launch_bounds__(256) void score_csr(
    const int* __restrict__ row_start, const int* __restrict__ csr_src,
    const float* __restrict__ ts, const float* __restrict__ td,
    const float* __restrict__ bp, float* __restrict__ score, int n)
{
    int i = blockIdx.x * 256 + threadIdx.x;
    if (i >= n) return;
    int beg = row_start[i], end = row_start[i + 1];
    float s = td[i] + bp[0];
    for (int j = beg; j < end; ++j) s += ts[csr_src[j]];
    score[i] = s;
}

// ---------------- precompute: va_l = W_l @ a; pad Wl/bl; zero deg ----------------
__global__ __launch_bounds__(256) void precompute(
    const float* __restrict__ W1, const float* __restrict__ a1s, const float* __restrict__ a1d,
    const float* __restrict__ W2, const float* __restrict__ a2s, const float* __restrict__ a2d,
    const float* __restrict__ W3, const float* __restrict__ a3s, const float* __restrict__ a3d,
    const float* __restrict__ Wl, const float* __restrict__ bl,
    float* __restrict__ va1, float* __restrict__ vb1,
    float* __restrict__ va2, float* __restrict__ vb2,
    float* __restrict__ va3, float* __restrict__ vb3,
    float* __restrict__ Wlp, float* __restrict__ blp,
    int* __restrict__ deg, int n)
{
    int t = blockIdx.x * 256 + threadIdx.x;
    if (t < n) deg[t] = 0;
    if (t < 128) {
        float sa = 0.f, sb = 0.f;
        for (int j = 0; j < 64; ++j) {
            float w = W1[t * 64 + j];
            sa = fmaf(w, a1s[j], sa); sb = fmaf(w, a1d[j], sb);
        }
        va1[t] = sa; vb1[t] = sb;
    } else if (t < 192) {
        int k = t - 128;
        float sa = 0.f, sb = 0.f;
        for (int j = 0; j < 128; ++j) {
            float w = W2[k * 128 + j];
            sa = fmaf(w, a2s[j], sa); sb = fmaf(w, a2d[j], sb);
        }
        va2[k] = sa; vb2[k] = sb;
    } else if (t < 320) {
        int k = t - 192;
        float sa = 0.f, sb = 0.f;
        for (int j = 0; j < 128; ++j) {
            float w = W3[k * 128 + j];
            sa = fmaf(w, a3s[j], sa); sb = fmaf(w, a3d[j], sb);
        }
        va3[k] = sa; vb3[k] = sb;
    } else if (t < 320 + 2048) {
        int i = t - 320;
        int k = i >> 4, c = i & 15;
        Wlp[i] = (c < 10) ? Wl[k * 10 + c] : 0.f;
    } else if (t < 320 + 2048 + 16) {
        int c = t - (320 + 2048);
        blp[c] = (c < 10) ? bl[c] : 0.f;
    }
}

extern "C" void kernel_launch(void* const* d_in, const int* in_sizes, int n_in,
                              void* d_out, int out_size, void* d_ws, size_t ws_size,
                              hipStream_t stream) {
    const float* x   = (const float*)d_in[0];
    const int*   ei  = (const int*)d_in[1];
    const float* W1  = (const float*)d_in[4];
    const float* a1s = (const float*)d_in[5];
    const float* a1d = (const float*)d_in[6];
    const float* b1  = (const float*)d_in[7];
    const float* W2  = (const float*)d_in[8];
    const float* a2s = (const float*)d_in[9];
    const float* a2d = (const float*)d_in[10];
    const float* b2  = (const float*)d_in[11];
    const float* W3  = (const float*)d_in[12];
    const float* a3s = (const float*)d_in[13];
    const float* a3d = (const float*)d_in[14];
    const float* b3  = (const float*)d_in[15];
    const float* wpr = (const float*)d_in[16];
    const float* wpo = (const float*)d_in[17];
    const float* bp  = (const float*)d_in[18];
    const float* Wl  = (const float*)d_in[19];
    const float* bl  = (const float*)d_in[20];

    const int n = in_sizes[0] / 128;   // 40000
    const int E = in_sizes[1] / 2;     // 640000
    const int* src = ei;
    const int* dst = ei + E;

    float* ws = (float*)d_ws;
    const size_t nd = (size_t)n * 128;
    float* bufA      = ws;                          // [n,128]
    float* bufB      = bufA + nd;                   // [n,128]
    float* asv       = bufB + nd;                   // [n]
    float* adv       = asv + n;                     // [n]
    float* tsv       = adv + n;                     // [n]
    float* tdv       = tsv + n;                     // [n]
    float* score     = tdv + n;                     // [n]
    int*   deg       = (int*)(score + n);           // [n]
    int*   row_start = deg + n;                     // [n+1]
    int*   cursor    = row_start + n + 1;           // [n]
    int*   blocksum  = cursor + n;                  // [<=256]
    int*   csr_src   = blocksum + 256;              // [E]
    float* va1       = (float*)(csr_src + E);       // [128]
    float* vb1       = va1 + 128;                   // [128]
    float* va2       = vb1 + 128;                   // [64]
    float* vb2       = va2 + 64;                    // [64]
    float* va3       = vb2 + 64;                    // [128]
    float* vb3       = va3 + 128;                   // [128]
    float* Wlp       = vb3 + 128;                   // [128*16]
    float* blp       = Wlp + 128 * 16;              // [16]

    const unsigned EB = (unsigned)((E + 255) / 256);
    const unsigned NB = (unsigned)((n + 255) / 256);
    const unsigned MB = (unsigned)((n + 63) / 64);   // 625
    const unsigned WB = (unsigned)(((size_t)n * 64 + 255) / 256);

    // ---------- precompute (+deg zero) + CSR build (original edges) ----------
    precompute<<<NB, 256, 0, stream>>>(W1, a1s, a1d, W2, a2s, a2d, W3, a3s, a3d, Wl, bl,
                                       va1, vb1, va2, vb2, va3, vb3, Wlp, blp, deg, n);
    hist_deg<<<EB, 256, 0, stream>>>(dst, deg, E);
    scan_local<<<NB, 256, 0, stream>>>(deg, row_start, blocksum, n);
    scan_blocks<<<1, 256, 0, stream>>>(blocksum, (int)NB);
    scan_add<<<NB, 256, 0, stream>>>(row_start, cursor, blocksum, n, E);
    fill_csr<<<EB, 256, 0, stream>>>(src, dst, cursor, csr_src, E);

    // ---------- Layer 1: 128 -> 64 ----------
    gemm_rt<128, 64, 64><<<dim3(MB, 1), 128, 0, stream>>>(
        x, W1, bufA, n, va1, vb1, asv, adv);
    gat_aggregate<64, false><<<WB, 256, 0, stream>>>(row_start, csr_src, asv, adv, bufA, b1, bufB,
                                                     nullptr, nullptr, nullptr, nullptr, n);

    // ---------- Layer 2: 64 -> 128 ----------
    gemm_rt<64, 128, 64><<<dim3(MB, 2), 128, 0, stream>>>(
        bufB, W2, bufA, n, va2, vb2, asv, adv);
    gat_aggregate<128, false><<<WB, 256, 0, stream>>>(row_start, csr_src, asv, adv, bufA, b2, bufB,
                                                      nullptr, nullptr, nullptr, nullptr, n);

    // ---------- Layer 3: 128 -> 128 ----------
    gemm_rt<128, 128, 64><<<dim3(MB, 2), 128, 0, stream>>>(
        bufB, W3, bufA, n, va3, vb3, asv, adv);
    gat_aggregate<128, true><<<WB, 256, 0, stream>>>(row_start, csr_src, asv, adv, bufA, b3, bufB,
                                                     wpr, wpo, tsv, tdv, n);

    // ---------- SAGPool score + final linear ----------
    score_csr<<<NB, 256, 0, stream>>>(row_start, csr_src, tsv, tdv, bp, score, n);
    gemm_tile<128, 16, 16><<<MB, 256, 0, stream>>>(bufB, Wlp, (float*)d_out, n, blp, score, 10);
}

// Round 15
// 295.464 us; speedup vs baseline: 1.0631x; 1.0038x over previous
//
#include <hip/hip_runtime.h>
#include <math.h>

// ---------------- register-tiled GEMM: C[M,N] = A[M,K] @ B[K,N] ----------------
// BM=64 rows/block, CPB cols/block (gridDim.y = N/CPB). 2*CPB threads,
// per-thread MR=4 rows x 8 cols. Reg->LDS staging, next chunk prefetched
// into registers right after the barrier (lands under the math).
// iva != nullptr (y==0 only): input dots ioa[r]=A_row.iva, iob[r]=A_row.ivb.
template<int K, int N, int CPB>
__global__ __launch_bounds__(2 * CPB) void gemm_rt(
    const float* __restrict__ A, const float* __restrict__ B,
    float* __restrict__ C, int M,
    const float* __restrict__ iva, const float* __restrict__ ivb,
    float* __restrict__ ioa, float* __restrict__ iob)
{
    constexpr int KC = 32;
    constexpr int NC = K / KC;
    constexpr int TC = CPB / 8;
    constexpr int NT = 2 * CPB;
    constexpr int KT = KC / TC;
    constexpr int AST = 68;
    constexpr int A_F4 = 512 / NT;
    constexpr int B_F4 = (KC * CPB / 4) / NT;

    __shared__ float AsT[KC * AST];
    __shared__ float Bs[KC * CPB];

    const int tid = threadIdx.x;
    const int base = blockIdx.x * 64;
    const int col0 = blockIdx.y * CPB;
    const int tc = tid % TC;
    const int tr = tid / TC;

    float acc[4][8];
#pragma unroll
    for (int m = 0; m < 4; ++m)
#pragma unroll
        for (int j = 0; j < 8; ++j) acc[m][j] = 0.f;
    float sa[4], sb[4];
#pragma unroll
    for (int m = 0; m < 4; ++m) { sa[m] = 0.f; sb[m] = 0.f; }

    float4 ra[A_F4], rb[B_F4];

#pragma unroll
    for (int j = 0; j < A_F4; ++j) {
        int i = tid + j * NT; int row = i >> 3; int q = i & 7;
        int gr = base + row;
        ra[j] = (gr < M) ? *(const float4*)(A + (size_t)gr * K + 4 * q)
                         : make_float4(0.f, 0.f, 0.f, 0.f);
    }
#pragma unroll
    for (int j = 0; j < B_F4; ++j) {
        int i = tid + j * NT; int kk_ = i / (CPB / 4); int c4 = i % (CPB / 4);
        rb[j] = *(const float4*)(B + (size_t)kk_ * N + col0 + 4 * c4);
    }

    for (int ch = 0; ch < NC; ++ch) {
#pragma unroll
        for (int j = 0; j < A_F4; ++j) {
            int i = tid + j * NT; int row = i >> 3; int q = i & 7;
            AsT[(4 * q + 0) * AST + row] = ra[j].x;
            AsT[(4 * q + 1) * AST + row] = ra[j].y;
            AsT[(4 * q + 2) * AST + row] = ra[j].z;
            AsT[(4 * q + 3) * AST + row] = ra[j].w;
        }
#pragma unroll
        for (int j = 0; j < B_F4; ++j) {
            int i = tid + j * NT; int kk_ = i / (CPB / 4); int c4 = i % (CPB / 4);
            *(float4*)(Bs + kk_ * CPB + 4 * c4) = rb[j];
        }
        __syncthreads();

        if (ch + 1 < NC) {
            const int k0 = (ch + 1) * KC;
#pragma unroll
            for (int j = 0; j < A_F4; ++j) {
                int i = tid + j * NT; int row = i >> 3; int q = i & 7;
                int gr = base + row;
                ra[j] = (gr < M) ? *(const float4*)(A + (size_t)gr * K + k0 + 4 * q)
                                 : make_float4(0.f, 0.f, 0.f, 0.f);
            }
#pragma unroll
            for (int j = 0; j < B_F4; ++j) {
                int i = tid + j * NT; int kk_ = i / (CPB / 4); int c4 = i % (CPB / 4);
                rb[j] = *(const float4*)(B + (size_t)(k0 + kk_) * N + col0 + 4 * c4);
            }
        }

#pragma unroll 8
        for (int kk = 0; kk < KC; ++kk) {
            float4 a0 = *(const float4*)(AsT + kk * AST + 4 * tr);
            const float* bp = Bs + kk * CPB + 8 * tc;
            float4 b0 = *(const float4*)(bp);
            float4 b1 = *(const float4*)(bp + 4);
#pragma unroll
            for (int m = 0; m < 4; ++m) {
                float av = ((const float*)&a0)[m];
                acc[m][0] = fmaf(av, b0.x, acc[m][0]);
                acc[m][1] = fmaf(av, b0.y, acc[m][1]);
                acc[m][2] = fmaf(av, b0.z, acc[m][2]);
                acc[m][3] = fmaf(av, b0.w, acc[m][3]);
                acc[m][4] = fmaf(av, b1.x, acc[m][4]);
                acc[m][5] = fmaf(av, b1.y, acc[m][5]);
                acc[m][6] = fmaf(av, b1.z, acc[m][6]);
                acc[m][7] = fmaf(av, b1.w, acc[m][7]);
            }
        }

        if (iva != nullptr && blockIdx.y == 0) {
            const int k0 = ch * KC;
#pragma unroll
            for (int kl = 0; kl < KT; ++kl) {
                int k = tc * KT + kl;
                float av_ = iva[k0 + k];
                float bv_ = ivb[k0 + k];
#pragma unroll
                for (int m = 0; m < 4; ++m) {
                    float aval = AsT[k * AST + 4 * tr + m];
                    sa[m] = fmaf(aval, av_, sa[m]);
                    sb[m] = fmaf(aval, bv_, sb[m]);
                }
            }
        }
        __syncthreads();
    }

#pragma unroll
    for (int m = 0; m < 4; ++m) {
        int gr = base + 4 * tr + m;
        if (gr < M) {
            *(float4*)(C + (size_t)gr * N + col0 + 8 * tc) =
                make_float4(acc[m][0], acc[m][1], acc[m][2], acc[m][3]);
            *(float4*)(C + (size_t)gr * N + col0 + 8 * tc + 4) =
                make_float4(acc[m][4], acc[m][5], acc[m][6], acc[m][7]);
        }
    }
    if (iva != nullptr && blockIdx.y == 0) {
#pragma unroll
        for (int m = 0; m < 4; ++m) {
#pragma unroll
            for (int off = TC / 2; off; off >>= 1) {
                sa[m] += __shfl_xor(sa[m], off);
                sb[m] += __shfl_xor(sb[m], off);
            }
        }
        if (tc == 0) {
#pragma unroll
            for (int m = 0; m < 4; ++m) {
                int gr = base + 4 * tr + m;
                if (gr < M) { ioa[gr] = sa[m]; iob[gr] = sb[m]; }
            }
        }
    }
}

// ---------------- small GEMM (final layer) ----------------
template<int K, int N, int NT>
__global__ __launch_bounds__(256) void gemm_tile(
    const float* __restrict__ A, const float* __restrict__ B,
    float* __restrict__ C, int M,
    const float* __restrict__ bias, const float* __restrict__ score, int outN)
{
    __shared__ float As[64 * K];
    const int tid = threadIdx.x;
    const int base = blockIdx.x * 64;
    for (int idx = tid; idx < 64 * K; idx += 256) {
        int r = idx / K, k = idx - r * K;
        int gr = base + r;
        As[idx] = (gr < M) ? A[(size_t)gr * K + k] : 0.f;
    }
    __syncthreads();
    constexpr int RSTEP = 256 / NT;
    constexpr int NR = 64 / RSTEP;
    const int c = tid % NT;
    const int r0 = tid / NT;
    float acc[NR];
#pragma unroll
    for (int i = 0; i < NR; ++i) acc[i] = 0.f;
    const float4* As4 = reinterpret_cast<const float4*>(As);
    const float* Bc = B + c;
    float b0 = Bc[0 * N], b1 = Bc[1 * N], b2 = Bc[2 * N], b3 = Bc[3 * N];
    for (int k = 0; k < K; k += 4) {
        const int kn = (k + 4 < K) ? (k + 4) : k;
        float n0 = Bc[(kn + 0) * N];
        float n1 = Bc[(kn + 1) * N];
        float n2 = Bc[(kn + 2) * N];
        float n3 = Bc[(kn + 3) * N];
#pragma unroll
        for (int i = 0; i < NR; ++i) {
            float4 a = As4[((r0 + i * RSTEP) * K + k) >> 2];
            acc[i] = fmaf(a.x, b0, acc[i]);
            acc[i] = fmaf(a.y, b1, acc[i]);
            acc[i] = fmaf(a.z, b2, acc[i]);
            acc[i] = fmaf(a.w, b3, acc[i]);
        }
        b0 = n0; b1 = n1; b2 = n2; b3 = n3;
    }
    if (c < outN) {
#pragma unroll
        for (int i = 0; i < NR; ++i) {
            int gr = base + r0 + i * RSTEP;
            if (gr < M) {
                float v = tanhf(score[gr]) * acc[i] + bias[c];
                C[(size_t)gr * outN + c] = fmaxf(v, 0.f);
            }
        }
    }
}

// ---------------- CSR build (ORIGINAL edges only; self-loops handled in-kernel) ----------------
__global__ __launch_bounds__(256) void hist_deg(
    const int* __restrict__ dst, int* __restrict__ deg, int E)
{
    int e = blockIdx.x * 256 + threadIdx.x;
    if (e < E) atomicAdd(deg + dst[e], 1);
}

__global__ __launch_bounds__(256) void scan_local(
    const int* __restrict__ deg, int* __restrict__ row_start, int* __restrict__ blocksum, int n)
{
    __shared__ int s[256];
    const int t = threadIdx.x;
    const int i = blockIdx.x * 256 + t;
    int v = (i < n) ? deg[i] : 0;
    s[t] = v;
    __syncthreads();
#pragma unroll
    for (int off = 1; off < 256; off <<= 1) {
        int u = (t >= off) ? s[t - off] : 0;
        __syncthreads();
        s[t] += u;
        __syncthreads();
    }
    if (i < n) row_start[i] = s[t] - v;
    if (t == 255) blocksum[blockIdx.x] = s[255];
}

__global__ __launch_bounds__(256) void scan_blocks(int* __restrict__ blocksum, int nb)
{
    __shared__ int s[256];
    const int t = threadIdx.x;
    int v = (t < nb) ? blocksum[t] : 0;
    s[t] = v;
    __syncthreads();
#pragma unroll
    for (int off = 1; off < 256; off <<= 1) {
        int u = (t >= off) ? s[t - off] : 0;
        __syncthreads();
        s[t] += u;
        __syncthreads();
    }
    if (t < nb) blocksum[t] = s[t] - v;
}

__global__ __launch_bounds__(256) void scan_add(
    int* __restrict__ row_start, int* __restrict__ cursor,
    const int* __restrict__ blocksum, int n, int total)
{
    const int i = blockIdx.x * 256 + threadIdx.x;
    if (i < n) {
        int v = row_start[i] + blocksum[blockIdx.x];
        row_start[i] = v;
        cursor[i] = v;
    } else if (i == n) {
        row_start[n] = total;
    }
}

__global__ __launch_bounds__(256) void fill_csr(
    const int* __restrict__ src, const int* __restrict__ dst,
    int* __restrict__ cursor, int* __restrict__ csr_src, int E)
{
    int e = blockIdx.x * 256 + threadIdx.x;
    if (e >= E) return;
    int pos = atomicAdd(cursor + dst[e], 1);
    csr_src[pos] = src[e];
}

// ---------------- fused GAT aggregation: one wave per node ----------------
// Merged exp+sum pass (no max subtraction: coef = exp(a)/Sum exp(a), exact in
// real arithmetic since exp(a-m)/Sum exp(a-m) cancels m; alpha bounded ~|2|).
// Self-loop handled in-register (CSR holds original edges only).
template<int D, bool POOL>
__global__ __launch_bounds__(256) void gat_aggregate(
    const int* __restrict__ row_start, const int* __restrict__ csr_src,
    const float* __restrict__ asv, const float* __restrict__ adv,
    const float* __restrict__ h, const float* __restrict__ bias,
    float* __restrict__ out,
    const float* __restrict__ wpr, const float* __restrict__ wpo,
    float* __restrict__ poolA, float* __restrict__ poolB, int n)
{
    __shared__ float lds_e[4][128];
    __shared__ int   lds_i[4][128];
    const int node = (blockIdx.x * 256 + threadIdx.x) >> 6;
    const int lane = threadIdx.x & 63;
    const int w = threadIdx.x >> 6;
    if (node >= n) return;
    const int beg = row_start[node];
    const int deg = row_start[node + 1] - beg;
    const float advv = adv[node];
    const bool fast = (deg <= 128);

    float a_self = asv[node] + advv;
    a_self = (a_self >= 0.f) ? a_self : 0.2f * a_self;
    const float ev_self = expf(a_self);

    float ssum = (lane == 0) ? ev_self : 0.f;
    if (fast) {
        for (int j = lane; j < deg; j += 64) {
            int s = csr_src[beg + j];
            lds_i[w][j] = s;
            float a = asv[s] + advv;
            a = (a >= 0.f) ? a : 0.2f * a;
            float ev = expf(a);
            lds_e[w][j] = ev;
            ssum += ev;
        }
    } else {
        for (int j = lane; j < deg; j += 64) {
            float a = asv[csr_src[beg + j]] + advv;
            a = (a >= 0.f) ? a : 0.2f * a;
            ssum += expf(a);
        }
    }
#pragma unroll
    for (int off = 32; off; off >>= 1) ssum += __shfl_xor(ssum, off);
    const float inv = 1.f / (ssum + 1e-16f);

    if (fast) {
        if constexpr (D == 128) {
            const float4* h4 = reinterpret_cast<const float4*>(h);
            const int half = lane >> 5;
            const int fl = lane & 31;
            float4 a0 = {0,0,0,0}, a1 = {0,0,0,0}, a2 = {0,0,0,0}, a3 = {0,0,0,0};
            int j = 0;
            for (; j + 8 <= deg; j += 8) {
                int e0 = j + half, e1 = j + 2 + half, e2 = j + 4 + half, e3 = j + 6 + half;
                int s0 = lds_i[w][e0], s1 = lds_i[w][e1], s2 = lds_i[w][e2], s3 = lds_i[w][e3];
                float c0 = lds_e[w][e0] * inv, c1 = lds_e[w][e1] * inv;
                float c2 = lds_e[w][e2] * inv, c3 = lds_e[w][e3] * inv;
                float4 v0 = h4[(size_t)s0 * 32 + fl];
                float4 v1 = h4[(size_t)s1 * 32 + fl];
                float4 v2 = h4[(size_t)s2 * 32 + fl];
                float4 v3 = h4[(size_t)s3 * 32 + fl];
                a0.x = fmaf(v0.x, c0, a0.x); a0.y = fmaf(v0.y, c0, a0.y);
                a0.z = fmaf(v0.z, c0, a0.z); a0.w = fmaf(v0.w, c0, a0.w);
                a1.x = fmaf(v1.x, c1, a1.x); a1.y = fmaf(v1.y, c1, a1.y);
                a1.z = fmaf(v1.z, c1, a1.z); a1.w = fmaf(v1.w, c1, a1.w);
                a2.x = fmaf(v2.x, c2, a2.x); a2.y = fmaf(v2.y, c2, a2.y);
                a2.z = fmaf(v2.z, c2, a2.z); a2.w = fmaf(v2.w, c2, a2.w);
                a3.x = fmaf(v3.x, c3, a3.x); a3.y = fmaf(v3.y, c3, a3.y);
                a3.z = fmaf(v3.z, c3, a3.z); a3.w = fmaf(v3.w, c3, a3.w);
            }
            for (; j < deg; j += 2) {
                int e = j + half;
                bool ok = (e < deg);
                int s = lds_i[w][ok ? e : 0];
                float c = ok ? lds_e[w][e] * inv : 0.f;
                float4 v = h4[(size_t)s * 32 + fl];
                a0.x = fmaf(v.x, c, a0.x); a0.y = fmaf(v.y, c, a0.y);
                a0.z = fmaf(v.z, c, a0.z); a0.w = fmaf(v.w, c, a0.w);
            }
            {   // self-loop (half 0 only; counted once)
                float c = (half == 0) ? ev_self * inv : 0.f;
                float4 v = h4[(size_t)node * 32 + fl];
                a1.x = fmaf(v.x, c, a1.x); a1.y = fmaf(v.y, c, a1.y);
                a1.z = fmaf(v.z, c, a1.z); a1.w = fmaf(v.w, c, a1.w);
            }
            float4 t;
            t.x = (a0.x + a1.x) + (a2.x + a3.x);
            t.y = (a0.y + a1.y) + (a2.y + a3.y);
            t.z = (a0.z + a1.z) + (a2.z + a3.z);
            t.w = (a0.w + a1.w) + (a2.w + a3.w);
            t.x += __shfl_xor(t.x, 32);
            t.y += __shfl_xor(t.y, 32);
            t.z += __shfl_xor(t.z, 32);
            t.w += __shfl_xor(t.w, 32);
            const float4 b4 = reinterpret_cast<const float4*>(bias)[fl];
            float4 o;
            o.x = fmaxf(t.x + b4.x, 0.f);
            o.y = fmaxf(t.y + b4.y, 0.f);
            o.z = fmaxf(t.z + b4.z, 0.f);
            o.w = fmaxf(t.w + b4.w, 0.f);
            if (half == 0)
                reinterpret_cast<float4*>(out)[(size_t)node * 32 + fl] = o;
            if constexpr (POOL) {
                const float4 r4 = reinterpret_cast<const float4*>(wpr)[fl];
                const float4 q4 = reinterpret_cast<const float4*>(wpo)[fl];
                float pa = o.x * r4.x + o.y * r4.y + o.z * r4.z + o.w * r4.w;
                float pb = o.x * q4.x + o.y * q4.y + o.z * q4.z + o.w * q4.w;
#pragma unroll
                for (int off = 16; off; off >>= 1) {
                    pa += __shfl_xor(pa, off);
                    pb += __shfl_xor(pb, off);
                }
                if (lane == 0) { poolA[node] = pa; poolB[node] = pb; }
            }
        } else {
            const float4* h4 = reinterpret_cast<const float4*>(h);
            const int q = lane >> 4;
            const int fl = lane & 15;
            float4 a0 = {0,0,0,0}, a1 = {0,0,0,0};
            int j = 0;
            for (; j + 8 <= deg; j += 8) {
                int e0 = j + q, e1 = j + 4 + q;
                int s0 = lds_i[w][e0], s1 = lds_i[w][e1];
                float c0 = lds_e[w][e0] * inv, c1 = lds_e[w][e1] * inv;
                float4 v0 = h4[(size_t)s0 * 16 + fl];
                float4 v1 = h4[(size_t)s1 * 16 + fl];
                a0.x = fmaf(v0.x, c0, a0.x); a0.y = fmaf(v0.y, c0, a0.y);
                a0.z = fmaf(v0.z, c0, a0.z); a0.w = fmaf(v0.w, c0, a0.w);
                a1.x = fmaf(v1.x, c1, a1.x); a1.y = fmaf(v1.y, c1, a1.y);
                a1.z = fmaf(v1.z, c1, a1.z); a1.w = fmaf(v1.w, c1, a1.w);
            }
            for (; j < deg; j += 4) {
                int e = j + q;
                bool ok = (e < deg);
                int s = lds_i[w][ok ? e : 0];
                float c = ok ? lds_e[w][e] * inv : 0.f;
                float4 v = h4[(size_t)s * 16 + fl];
                a0.x = fmaf(v.x, c, a0.x); a0.y = fmaf(v.y, c, a0.y);
                a0.z = fmaf(v.z, c, a0.z); a0.w = fmaf(v.w, c, a0.w);
            }
            {   // self-loop (q 0 only)
                float c = (q == 0) ? ev_self * inv : 0.f;
                float4 v = h4[(size_t)node * 16 + fl];
                a1.x = fmaf(v.x, c, a1.x); a1.y = fmaf(v.y, c, a1.y);
                a1.z = fmaf(v.z, c, a1.z); a1.w = fmaf(v.w, c, a1.w);
            }
            float4 t;
            t.x = a0.x + a1.x; t.y = a0.y + a1.y; t.z = a0.z + a1.z; t.w = a0.w + a1.w;
            t.x += __shfl_xor(t.x, 16); t.x += __shfl_xor(t.x, 32);
            t.y += __shfl_xor(t.y, 16); t.y += __shfl_xor(t.y, 32);
            t.z += __shfl_xor(t.z, 16); t.z += __shfl_xor(t.z, 32);
            t.w += __shfl_xor(t.w, 16); t.w += __shfl_xor(t.w, 32);
            const float4 b4 = reinterpret_cast<const float4*>(bias)[fl];
            float4 o;
            o.x = fmaxf(t.x + b4.x, 0.f);
            o.y = fmaxf(t.y + b4.y, 0.f);
            o.z = fmaxf(t.z + b4.z, 0.f);
            o.w = fmaxf(t.w + b4.w, 0.f);
            if (q == 0)
                reinterpret_cast<float4*>(out)[(size_t)node * 16 + fl] = o;
        }
    } else {
        // slow path (deg > 128): recompute exp per edge
        if constexpr (D == 128) {
            const float2* h2 = reinterpret_cast<const float2*>(h);
            float2 a0 = {0.f, 0.f};
            for (int j = 0; j < deg; ++j) {
                int s = csr_src[beg + j];
                float a = asv[s] + advv;
                a = (a >= 0.f) ? a : 0.2f * a;
                float c = expf(a) * inv;
                float2 v = h2[(size_t)s * 64 + lane];
                a0.x = fmaf(v.x, c, a0.x); a0.y = fmaf(v.y, c, a0.y);
            }
            {
                float c = ev_self * inv;
                float2 v = h2[(size_t)node * 64 + lane];
                a0.x = fmaf(v.x, c, a0.x); a0.y = fmaf(v.y, c, a0.y);
            }
            float2 o;
            o.x = fmaxf(a0.x + bias[2 * lane], 0.f);
            o.y = fmaxf(a0.y + bias[2 * lane + 1], 0.f);
            reinterpret_cast<float2*>(out)[(size_t)node * 64 + lane] = o;
            if constexpr (POOL) {
                float pa = fmaf(o.x, wpr[2 * lane], o.y * wpr[2 * lane + 1]);
                float pb = fmaf(o.x, wpo[2 * lane], o.y * wpo[2 * lane + 1]);
#pragma unroll
                for (int off = 32; off; off >>= 1) {
                    pa += __shfl_xor(pa, off);
                    pb += __shfl_xor(pb, off);
                }
                if (lane == 0) { poolA[node] = pa; poolB[node] = pb; }
            }
        } else {
            float a0 = 0.f;
            for (int j = 0; j < deg; ++j) {
                int s = csr_src[beg + j];
                float a = asv[s] + advv;
                a = (a >= 0.f) ? a : 0.2f * a;
                a0 = fmaf(h[(size_t)s * D + lane], expf(a) * inv, a0);
            }
            a0 = fmaf(h[(size_t)node * D + lane], ev_self * inv, a0);
            out[(size_t)node * D + lane] = fmaxf(a0 + bias[lane], 0.f);
        }
    }
}

// ---------------- pooling score via CSR (original edges; no self-loops here) ----------------
__global__ __launch_bounds__(256) void score_csr(
    const int* __restrict__ row_start, const int* __restrict__ csr_src,
    const float* __restrict__ ts, const float* __restrict__ td,
    const float* __restrict__ bp, float* __restrict__ score, int n)
{
    int i = blockIdx.x * 256 + threadIdx.x;
    if (i >= n) return;
    int beg = row_start[i], end = row_start[i + 1];
    float s = td[i] + bp[0];
    for (int j = beg; j < end; ++j) s += ts[csr_src[j]];
    score[i] = s;
}

// ---------------- precompute: va_l = W_l @ a; pad Wl/bl; zero deg ----------------
__global__ __launch_bounds__(256) void precompute(
    const float* __restrict__ W1, const float* __restrict__ a1s, const float* __restrict__ a1d,
    const float* __restrict__ W2, const float* __restrict__ a2s, const float* __restrict__ a2d,
    const float* __restrict__ W3, const float* __restrict__ a3s, const float* __restrict__ a3d,
    const float* __restrict__ Wl, const float* __restrict__ bl,
    float* __restrict__ va1, float* __restrict__ vb1,
    float* __restrict__ va2, float* __restrict__ vb2,
    float* __restrict__ va3, float* __restrict__ vb3,
    float* __restrict__ Wlp, float* __restrict__ blp,
    int* __restrict__ deg, int n)
{
    int t = blockIdx.x * 256 + threadIdx.x;
    if (t < n) deg[t] = 0;
    if (t < 128) {
        float sa = 0.f, sb = 0.f;
        for (int j = 0; j < 64; ++j) {
            float w = W1[t * 64 + j];
            sa = fmaf(w, a1s[j], sa); sb = fmaf(w, a1d[j], sb);
        }
        va1[t] = sa; vb1[t] = sb;
    } else if (t < 192) {
        int k = t - 128;
        float sa = 0.f, sb = 0.f;
        for (int j = 0; j < 128; ++j) {
            float w = W2[k * 128 + j];
            sa = fmaf(w, a2s[j], sa); sb = fmaf(w, a2d[j], sb);
        }
        va2[k] = sa; vb2[k] = sb;
    } else if (t < 320) {
        int k = t - 192;
        float sa = 0.f, sb = 0.f;
        for (int j = 0; j < 128; ++j) {
            float w = W3[k * 128 + j];
            sa = fmaf(w, a3s[j], sa); sb = fmaf(w, a3d[j], sb);
        }
        va3[k] = sa; vb3[k] = sb;
    } else if (t < 320 + 2048) {
        int i = t - 320;
        int k = i >> 4, c = i & 15;
        Wlp[i] = (c < 10) ? Wl[k * 10 + c] : 0.f;
    } else if (t < 320 + 2048 + 16) {
        int c = t - (320 + 2048);
        blp[c] = (c < 10) ? bl[c] : 0.f;
    }
}

extern "C" void kernel_launch(void* const* d_in, const int* in_sizes, int n_in,
                              void* d_out, int out_size, void* d_ws, size_t ws_size,
                              hipStream_t stream) {
    const float* x   = (const float*)d_in[0];
    const int*   ei  = (const int*)d_in[1];
    const float* W1  = (const float*)d_in[4];
    const float* a1s = (const float*)d_in[5];
    const float* a1d = (const float*)d_in[6];
    const float* b1  = (const float*)d_in[7];
    const float* W2  = (const float*)d_in[8];
    const float* a2s = (const float*)d_in[9];
    const float* a2d = (const float*)d_in[10];
    const float* b2  = (const float*)d_in[11];
    const float* W3  = (const float*)d_in[12];
    const float* a3s = (const float*)d_in[13];
    const float* a3d = (const float*)d_in[14];
    const float* b3  = (const float*)d_in[15];
    const float* wpr = (const float*)d_in[16];
    const float* wpo = (const float*)d_in[17];
    const float* bp  = (const float*)d_in[18];
    const float* Wl  = (const float*)d_in[19];
    const float* bl  = (const float*)d_in[20];

    const int n = in_sizes[0] / 128;   // 40000
    const int E = in_sizes[1] / 2;     // 640000
    const int* src = ei;
    const int* dst = ei + E;

    float* ws = (float*)d_ws;
    const size_t nd = (size_t)n * 128;
    float* bufA      = ws;                          // [n,128]
    float* bufB      = bufA + nd;                   // [n,128]
    float* asv       = bufB + nd;                   // [n]
    float* adv       = asv + n;                     // [n]
    float* tsv       = adv + n;                     // [n]
    float* tdv       = tsv + n;                     // [n]
    float* score     = tdv + n;                     // [n]
    int*   deg       = (int*)(score + n);           // [n]
    int*   row_start = deg + n;                     // [n+1]
    int*   cursor    = row_start + n + 1;           // [n]
    int*   blocksum  = cursor + n;                  // [<=256]
    int*   csr_src   = blocksum + 256;              // [E]
    float* va1       = (float*)(csr_src + E);       // [128]
    float* vb1       = va1 + 128;                   // [128]
    float* va2       = vb1 + 128;                   // [64]
    float* vb2       = va2 + 64;                    // [64]
    float* va3       = vb2 + 64;                    // [128]
    float* vb3       = va3 + 128;                   // [128]
    float* Wlp       = vb3 + 128;                   // [128*16]
    float* blp       = Wlp + 128 * 16;              // [16]

    const unsigned EB = (unsigned)((E + 255) / 256);
    const unsigned NB = (unsigned)((n + 255) / 256);
    const unsigned MB = (unsigned)((n + 63) / 64);   // 625
    const unsigned WB = (unsigned)(((size_t)n * 64 + 255) / 256);

    // ---------- precompute (+deg zero) + CSR build (original edges) ----------
    precompute<<<NB, 256, 0, stream>>>(W1, a1s, a1d, W2, a2s, a2d, W3, a3s, a3d, Wl, bl,
                                       va1, vb1, va2, vb2, va3, vb3, Wlp, blp, deg, n);
    hist_deg<<<EB, 256, 0, stream>>>(dst, deg, E);
    scan_local<<<NB, 256, 0, stream>>>(deg, row_start, blocksum, n);
    scan_blocks<<<1, 256, 0, stream>>>(blocksum, (int)NB);
    scan_add<<<NB, 256, 0, stream>>>(row_start, cursor, blocksum, n, E);
    fill_csr<<<EB, 256, 0, stream>>>(src, dst, cursor, csr_src, E);

    // ---------- Layer 1: 128 -> 64 ----------
    gemm_rt<128, 64, 64><<<dim3(MB, 1), 128, 0, stream>>>(
        x, W1, bufA, n, va1, vb1, asv, adv);
    gat_aggregate<64, false><<<WB, 256, 0, stream>>>(row_start, csr_src, asv, adv, bufA, b1, bufB,
                                                     nullptr, nullptr, nullptr, nullptr, n);

    // ---------- Layer 2: 64 -> 128 ----------
    gemm_rt<64, 128, 64><<<dim3(MB, 2), 128, 0, stream>>>(
        bufB, W2, bufA, n, va2, vb2, asv, adv);
    gat_aggregate<128, false><<<WB, 256, 0, stream>>>(row_start, csr_src, asv, adv, bufA, b2, bufB,
                                                      nullptr, nullptr, nullptr, nullptr, n);

    // ---------- Layer 3: 128 -> 128 ----------
    gemm_rt<128, 128, 64><<<dim3(MB, 2), 128, 0, stream>>>(
        bufB, W3, bufA, n, va3, vb3, asv, adv);
    gat_aggregate<128, true><<<WB, 256, 0, stream>>>(row_start, csr_src, asv, adv, bufA, b3, bufB,
                                                     wpr, wpo, tsv, tdv, n);

    // ---------- SAGPool score + final linear ----------
    score_csr<<<NB, 256, 0, stream>>>(row_start, csr_src, tsv, tdv, bp, score, n);
    gemm_tile<128, 16, 16><<<MB, 256, 0, stream>>>(bufB, Wlp, (float*)d_out, n, blp, score, 10);
}